// Round 10
// baseline (338.645 us; speedup 1.0000x reference)
//
#include <hip/hip_runtime.h>

#define NN 50000
#define NE 800000
#define F 128
#define EPS 1e-5f
#define FILLB 391    // ceil(NE / 2048): fill blocks, 8 edges/thread (matches hist chunking)
#define GEMMB 782    // ceil(NN / 64) gemm blocks
#define FUSEDB (FILLB + GEMMB)

typedef __attribute__((ext_vector_type(8))) short bf16x8;
typedef __attribute__((ext_vector_type(4))) float f32x4;

__device__ inline unsigned short f2bf_rn(float f) {
    unsigned u = __builtin_bit_cast(unsigned, f);
    u += 0x7fffu + ((u >> 16) & 1u);
    return (unsigned short)(u >> 16);
}
__device__ inline float bf2f(unsigned short h) {
    unsigned u = ((unsigned)h) << 16;
    return __builtin_bit_cast(float, u);
}
__device__ inline float bflo(unsigned u) {                 // low bf16 of packed pair -> f32
    return __builtin_bit_cast(float, u << 16);
}
__device__ inline float bfhi(unsigned u) {                 // high bf16 of packed pair -> f32
    return __builtin_bit_cast(float, u & 0xffff0000u);
}

// ---------------- degree / CSR build (8-way XCD-privatized) ----------------
// hist block b counts edges [b*2048, (b+1)*2048) into copy b&7. The fused fill
// uses fill-ordinal fb over the SAME 2048-edge chunks with group fb&7, so the
// edge->group map is identical and each cursor copy is touched by one XCD.

__global__ __launch_bounds__(256) void hist_k(const int* __restrict__ dst, int* __restrict__ deg8, int E) {
    int base = (blockIdx.x * 256 + threadIdx.x) * 8;
    if (base >= E) return;
    int* dg = deg8 + (blockIdx.x & 7) * NN;
    int4 d0 = *(const int4*)&dst[base];
    int4 d1 = *(const int4*)&dst[base + 4];
    atomicAdd(&dg[d0.x], 1); atomicAdd(&dg[d0.y], 1);
    atomicAdd(&dg[d0.z], 1); atomicAdd(&dg[d0.w], 1);
    atomicAdd(&dg[d1.x], 1); atomicAdd(&dg[d1.y], 1);
    atomicAdd(&dg[d1.z], 1); atomicAdd(&dg[d1.w], 1);
}

__global__ __launch_bounds__(256) void block_sums_k(const int* __restrict__ deg8, int* __restrict__ bsum, int N) {
    __shared__ int s[256];
    int t = threadIdx.x;
    int i = blockIdx.x * 256 + t;
    int v = 0;
    if (i < N) {
#pragma unroll
        for (int g = 0; g < 8; ++g) v += deg8[g * NN + i];
    }
    s[t] = v;
    __syncthreads();
    for (int off = 128; off > 0; off >>= 1) {
        if (t < off) s[t] += s[t + off];
        __syncthreads();
    }
    if (t == 0) bsum[blockIdx.x] = s[0];
}

__global__ __launch_bounds__(256) void scan_partials_k(const int* __restrict__ bsum, int* __restrict__ bpre, int nb) {
    __shared__ int s[256];
    int t = threadIdx.x;
    int v = (t < nb) ? bsum[t] : 0;
    s[t] = v;
    __syncthreads();
    for (int off = 1; off < 256; off <<= 1) {
        int add = (t >= off) ? s[t - off] : 0;
        __syncthreads();
        s[t] += add;
        __syncthreads();
    }
    if (t < nb) bpre[t] = s[t] - v;   // exclusive
}

__global__ __launch_bounds__(256) void scan_final_k(const int* __restrict__ deg8, const int* __restrict__ bpre,
                                                    int* __restrict__ rp, int* __restrict__ fillcur,
                                                    float* __restrict__ dinv, int N, int E) {
    __shared__ int s[256];
    int t = threadIdx.x;
    int i = blockIdx.x * 256 + t;
    int c[8];
    int v = 0;
#pragma unroll
    for (int g = 0; g < 8; ++g) {
        c[g] = (i < N) ? deg8[g * NN + i] : 0;
        v += c[g];
    }
    s[t] = v;
    __syncthreads();
    for (int off = 1; off < 256; off <<= 1) {
        int add = (t >= off) ? s[t - off] : 0;
        __syncthreads();
        s[t] += add;
        __syncthreads();
    }
    int excl = s[t] - v + bpre[blockIdx.x];
    if (i < N) {
        rp[i] = excl;
        int run = excl;
#pragma unroll
        for (int g = 0; g < 8; ++g) {
            fillcur[g * NN + i] = run;   // per-group cursor start
            run += c[g];
        }
        dinv[i] = rsqrtf((float)v + 1.0f);
    }
    if (i == 0) rp[N] = E;
}

// ---------------- W pre-pack into MFMA B-fragment order (bf16 hi/lo), all 4 layers ----------------

__global__ __launch_bounds__(256) void pack_all_k(const float* __restrict__ W0, const float* __restrict__ W1,
                                                  const float* __restrict__ W2, const float* __restrict__ W3,
                                                  unsigned short* __restrict__ wh, unsigned short* __restrict__ wl) {
    int gidx = blockIdx.x * 256 + threadIdx.x;     // 0..65535
    int layer = gidx >> 14;
    int idx = gidx & 16383;
    const float* W = (layer == 0) ? W0 : (layer == 1) ? W1 : (layer == 2) ? W2 : W3;
    int i = idx & 7;
    int l = (idx >> 3) & 63;
    int n = (idx >> 9) & 7;
    int s = idx >> 12;
    int h = i >> 2, j = i & 3;
    int k = 32 * s + 4 * (l >> 4) + j + 16 * h;
    int c = 16 * n + (l & 15);
    float f = W[k * F + c];
    unsigned short hb = f2bf_rn(f);
    float rest = f - bf2f(hb);
    unsigned short lb = f2bf_rn(rest);
    wh[gidx] = hb;
    wl[gidx] = lb;
}

// ---------------- FUSED fill + layer-1 GEMM, INTERLEAVED grid ----------------
// 1 fill : 2 gemm interleave (R9, proven). NEW: col scatter uses nontemporal
// stores — each 64B col line receives entries from ~16 different blocks/XCDs,
// so regular stores ping-pong the line between per-XCD L2s (RFO + dirty
// eviction per 4B write, ~45MB HBM write amplification). NT stores write
// through without L2 ownership; merging happens in the shared L3/MC.

__global__ __launch_bounds__(256, 2) void fused_fill_gemm_k(const int* __restrict__ src, const int* __restrict__ dst,
                                                            int* __restrict__ fillcur, int* __restrict__ col, int E,
                                                            const float* __restrict__ A,
                                                            const unsigned short* __restrict__ wh,
                                                            const unsigned short* __restrict__ wl,
                                                            const float* __restrict__ dinv,
                                                            unsigned short* __restrict__ Hb, int M) {
    const int bid = blockIdx.x;
    if (bid % 3 == 0) {
        // ---- fill body (8 edges/thread), fill-ordinal fb = bid/3 ----
        int fb = bid / 3;                       // 0..FILLB-1, chunk of 2048 edges
        int base = (fb * 256 + threadIdx.x) * 8;
        if (base >= E) return;
        int* fc = fillcur + (fb & 7) * NN;      // same edge->group map as hist_k
        int4 d0 = *(const int4*)&dst[base];
        int4 d1 = *(const int4*)&dst[base + 4];
        int4 s0 = *(const int4*)&src[base];
        int4 s1 = *(const int4*)&src[base + 4];
        int p0 = atomicAdd(&fc[d0.x], 1);
        int p1 = atomicAdd(&fc[d0.y], 1);
        int p2 = atomicAdd(&fc[d0.z], 1);
        int p3 = atomicAdd(&fc[d0.w], 1);
        int p4 = atomicAdd(&fc[d1.x], 1);
        int p5 = atomicAdd(&fc[d1.y], 1);
        int p6 = atomicAdd(&fc[d1.z], 1);
        int p7 = atomicAdd(&fc[d1.w], 1);
        __builtin_nontemporal_store(s0.x, &col[p0]);
        __builtin_nontemporal_store(s0.y, &col[p1]);
        __builtin_nontemporal_store(s0.z, &col[p2]);
        __builtin_nontemporal_store(s0.w, &col[p3]);
        __builtin_nontemporal_store(s1.x, &col[p4]);
        __builtin_nontemporal_store(s1.y, &col[p5]);
        __builtin_nontemporal_store(s1.z, &col[p6]);
        __builtin_nontemporal_store(s1.w, &col[p7]);
        return;
    }

    // ---- gemm_conv body, gemm-ordinal gb = bid - bid/3 - 1 ----
    const int gb = bid - bid / 3 - 1;           // 0..GEMMB-1
    const int tid = threadIdx.x;
    const int w = tid >> 6;
    const int l = tid & 63;
    const int lr = l & 15;
    const int g = l >> 4;
    const int row0 = gb * 64;
    const int arow = min(row0 + w * 16 + lr, M - 1);
    const float* ap = A + (size_t)arow * F + g * 4;

    float4 af[4][2];
#pragma unroll
    for (int s = 0; s < 4; ++s) {
        af[s][0] = *(const float4*)(ap + s * 32);
        af[s][1] = *(const float4*)(ap + s * 32 + 16);
    }

    const unsigned short* bh = wh + (size_t)l * 8;
    const unsigned short* bl = wl + (size_t)l * 8;
    bf16x8 Bh[2][8], Bl[2][8];
#pragma unroll
    for (int n = 0; n < 8; ++n) {
        Bh[0][n] = *(const bf16x8*)(bh + (size_t)n * 512);
        Bl[0][n] = *(const bf16x8*)(bl + (size_t)n * 512);
    }

    bf16x8 ah[4], al[4];
#pragma unroll
    for (int s = 0; s < 4; ++s) {
#pragma unroll
        for (int i = 0; i < 8; ++i) {
            float f = (i < 4) ? (&af[s][0].x)[i] : (&af[s][1].x)[i - 4];
            unsigned short hb = f2bf_rn(f);
            ah[s][i] = (short)hb;
            al[s][i] = (short)f2bf_rn(f - bf2f(hb));
        }
    }

    f32x4 acc[8] = {};
#pragma unroll
    for (int s = 0; s < 4; ++s) {
        const int cur = s & 1, nxt = cur ^ 1;
        if (s < 3) {
#pragma unroll
            for (int n = 0; n < 8; ++n) {
                Bh[nxt][n] = *(const bf16x8*)(bh + (size_t)((s + 1) * 8 + n) * 512);
                Bl[nxt][n] = *(const bf16x8*)(bl + (size_t)((s + 1) * 8 + n) * 512);
            }
        }
#pragma unroll
        for (int n = 0; n < 8; ++n) {
            acc[n] = __builtin_amdgcn_mfma_f32_16x16x32_bf16(ah[s], Bh[cur][n], acc[n], 0, 0, 0);
            acc[n] = __builtin_amdgcn_mfma_f32_16x16x32_bf16(al[s], Bh[cur][n], acc[n], 0, 0, 0);
            acc[n] = __builtin_amdgcn_mfma_f32_16x16x32_bf16(ah[s], Bl[cur][n], acc[n], 0, 0, 0);
        }
    }

    float di[4];
#pragma unroll
    for (int r = 0; r < 4; ++r) {
        int row = row0 + w * 16 + g * 4 + r;
        di[r] = (row < M) ? dinv[row] : 0.f;
    }
#pragma unroll
    for (int n = 0; n < 8; ++n) {
#pragma unroll
        for (int r = 0; r < 4; ++r) {
            int row = row0 + w * 16 + g * 4 + r;
            if (row < M) Hb[(size_t)row * F + n * 16 + lr] = f2bf_rn(acc[n][r] * di[r]);
        }
    }
}

// ---------------- MFMA GEMM, layers 2-4: A pre-split hi/lo bf16 in FRAGMENT order ----------------
// acth/actl row layout: element f = 32s+16h+4g+j stored at pos = (g*4+s)*8 + 4h+j.

__global__ __launch_bounds__(256, 2) void gemm_split_k(const unsigned short* __restrict__ Ah,
                                                       const unsigned short* __restrict__ Al,
                                                       const unsigned short* __restrict__ wh,
                                                       const unsigned short* __restrict__ wl,
                                                       const float* __restrict__ dinv,
                                                       unsigned short* __restrict__ Hb, int M) {
    const int tid = threadIdx.x;
    const int w = tid >> 6;
    const int l = tid & 63;
    const int lr = l & 15;
    const int g = l >> 4;
    const int row0 = blockIdx.x * 64;
    const int arow = min(row0 + w * 16 + lr, M - 1);
    const unsigned short* ahp = Ah + (size_t)arow * F;
    const unsigned short* alp = Al + (size_t)arow * F;

    bf16x8 ah[4], al[4];
#pragma unroll
    for (int s = 0; s < 4; ++s) {
        ah[s] = *(const bf16x8*)(ahp + (g * 4 + s) * 8);
        al[s] = *(const bf16x8*)(alp + (g * 4 + s) * 8);
    }

    const unsigned short* bh = wh + (size_t)l * 8;
    const unsigned short* bl = wl + (size_t)l * 8;
    bf16x8 Bh[2][8], Bl[2][8];
#pragma unroll
    for (int n = 0; n < 8; ++n) {
        Bh[0][n] = *(const bf16x8*)(bh + (size_t)n * 512);
        Bl[0][n] = *(const bf16x8*)(bl + (size_t)n * 512);
    }

    f32x4 acc[8] = {};
#pragma unroll
    for (int s = 0; s < 4; ++s) {
        const int cur = s & 1, nxt = cur ^ 1;
        if (s < 3) {
#pragma unroll
            for (int n = 0; n < 8; ++n) {
                Bh[nxt][n] = *(const bf16x8*)(bh + (size_t)((s + 1) * 8 + n) * 512);
                Bl[nxt][n] = *(const bf16x8*)(bl + (size_t)((s + 1) * 8 + n) * 512);
            }
        }
#pragma unroll
        for (int n = 0; n < 8; ++n) {
            acc[n] = __builtin_amdgcn_mfma_f32_16x16x32_bf16(ah[s], Bh[cur][n], acc[n], 0, 0, 0);
            acc[n] = __builtin_amdgcn_mfma_f32_16x16x32_bf16(al[s], Bh[cur][n], acc[n], 0, 0, 0);
            acc[n] = __builtin_amdgcn_mfma_f32_16x16x32_bf16(ah[s], Bl[cur][n], acc[n], 0, 0, 0);
        }
    }

    float di[4];
#pragma unroll
    for (int r = 0; r < 4; ++r) {
        int row = row0 + w * 16 + g * 4 + r;
        di[r] = (row < M) ? dinv[row] : 0.f;
    }
#pragma unroll
    for (int n = 0; n < 8; ++n) {
#pragma unroll
        for (int r = 0; r < 4; ++r) {
            int row = row0 + w * 16 + g * 4 + r;
            if (row < M) Hb[(size_t)row * F + n * 16 + lr] = f2bf_rn(acc[n][r] * di[r]);
        }
    }
}

// ---------------- aggregation core (R6-proven) ----------------
// Full 16-batches: no clamp/mask, 32-bit saddr addressing; ONE masked tail batch.
// NEW: col reads are nontemporal — col streams through exactly once per pass;
// the NT hint keeps it from evicting Hb lines whose L2 re-use is what holds
// FETCH at 83MB instead of the 204MB logical gather traffic.

__device__ inline void gather_row16(const unsigned short* __restrict__ Hb, const int* __restrict__ col,
                                    int e0, int e1, int lane, float& sxo, float& syo) {
    const unsigned char* hbb = (const unsigned char*)Hb;
    const unsigned loff = (unsigned)lane << 2;
    float sx = 0.f, sy = 0.f;
    int e = e0;
    int nfull = (e1 - e0) >> 4;
    for (int bt = 0; bt < nfull; ++bt, e += 16) {
        int c[16];
#pragma unroll
        for (int j = 0; j < 16; ++j) c[j] = __builtin_nontemporal_load(&col[e + j]);
        unsigned hv[16];
#pragma unroll
        for (int j = 0; j < 16; ++j) hv[j] = *(const unsigned*)(hbb + (((unsigned)c[j] << 8) + loff));
#pragma unroll
        for (int j = 0; j < 16; ++j) { sx += bflo(hv[j]); sy += bfhi(hv[j]); }
    }
    if (e < e1) {
        int c[16];
#pragma unroll
        for (int j = 0; j < 16; ++j) c[j] = __builtin_nontemporal_load(&col[min(e + j, e1 - 1)]);
        unsigned hv[16];
#pragma unroll
        for (int j = 0; j < 16; ++j) hv[j] = *(const unsigned*)(hbb + (((unsigned)c[j] << 8) + loff));
#pragma unroll
        for (int j = 0; j < 16; ++j) hv[j] = (e + j < e1) ? hv[j] : 0u;
#pragma unroll
        for (int j = 0; j < 16; ++j) { sx += bflo(hv[j]); sy += bfhi(hv[j]); }
    }
    sxo = sx; syo = sy;
}

// ---------------- agg + BN + ReLU, layers 1-3: write hi/lo bf16 act in fragment order ----------------

__global__ __launch_bounds__(256) void agg_split_k(const unsigned short* __restrict__ Hb, const int* __restrict__ rp,
                                                   const int* __restrict__ col, const float* __restrict__ dinv,
                                                   const float* __restrict__ b, const float* __restrict__ g,
                                                   const float* __restrict__ be, const float* __restrict__ m,
                                                   const float* __restrict__ v,
                                                   unsigned short* __restrict__ acth, unsigned short* __restrict__ actl,
                                                   int N) {
    int wid = threadIdx.x >> 6;
    int lane = threadIdx.x & 63;
    int row = blockIdx.x * 4 + wid;
    if (row >= N) return;

    int e0 = rp[row], e1 = rp[row + 1];
    float sx, sy;
    gather_row16(Hb, col, e0, e1, lane, sx, sy);

    float di = dinv[row];
    unsigned hs = *(const unsigned*)((const unsigned char*)Hb + (((unsigned)row << 8) + ((unsigned)lane << 2)));
    float hsx = bflo(hs);
    float hsy = bfhi(hs);
    int f0 = 2 * lane, f1 = f0 + 1;
    float rx = (sx + hsx) * di + b[f0];
    float ry = (sy + hsy) * di + b[f1];
    float ax = rsqrtf(v[f0] + EPS) * g[f0];
    float ay = rsqrtf(v[f1] + EPS) * g[f1];
    rx = fmaf(rx - m[f0], ax, be[f0]);
    ry = fmaf(ry - m[f1], ay, be[f1]);
    rx = fmaxf(rx, 0.f);
    ry = fmaxf(ry, 0.f);

    // hi/lo split, stored at fragment-order position of f0 (f1 = f0+1 is adjacent)
    unsigned short hx = f2bf_rn(rx);
    unsigned short lx = f2bf_rn(rx - bf2f(hx));
    unsigned short hy = f2bf_rn(ry);
    unsigned short ly = f2bf_rn(ry - bf2f(hy));
    int j = f0 & 3, gq = (f0 >> 2) & 3, h = (f0 >> 4) & 1, s = f0 >> 5;
    int pos = (gq * 4 + s) * 8 + h * 4 + j;
    *(unsigned*)&acth[(size_t)row * F + pos] = (unsigned)hx | ((unsigned)hy << 16);
    *(unsigned*)&actl[(size_t)row * F + pos] = (unsigned)lx | ((unsigned)ly << 16);
}

// ---------------- agg + BN + ReLU, layer 4: write fp32 act ----------------

__global__ __launch_bounds__(256) void agg_fp32_k(const unsigned short* __restrict__ Hb, const int* __restrict__ rp,
                                                  const int* __restrict__ col, const float* __restrict__ dinv,
                                                  const float* __restrict__ b, const float* __restrict__ g,
                                                  const float* __restrict__ be, const float* __restrict__ m,
                                                  const float* __restrict__ v,
                                                  float* __restrict__ out, int N) {
    int wid = threadIdx.x >> 6;
    int lane = threadIdx.x & 63;
    int row = blockIdx.x * 4 + wid;
    if (row >= N) return;

    int e0 = rp[row], e1 = rp[row + 1];
    float sx, sy;
    gather_row16(Hb, col, e0, e1, lane, sx, sy);

    float di = dinv[row];
    unsigned hs = *(const unsigned*)((const unsigned char*)Hb + (((unsigned)row << 8) + ((unsigned)lane << 2)));
    float hsx = bflo(hs);
    float hsy = bfhi(hs);
    int f0 = 2 * lane, f1 = f0 + 1;
    float rx = (sx + hsx) * di + b[f0];
    float ry = (sy + hsy) * di + b[f1];
    float ax = rsqrtf(v[f0] + EPS) * g[f0];
    float ay = rsqrtf(v[f1] + EPS) * g[f1];
    rx = fmaf(rx - m[f0], ax, be[f0]);
    ry = fmaf(ry - m[f1], ay, be[f1]);
    rx = fmaxf(rx, 0.f);
    ry = fmaxf(ry, 0.f);
    float2 o = {rx, ry};
    *(float2*)&out[(size_t)row * F + 2 * lane] = o;
}

// ---------------- final: out[N,10] = act @ w_out[128,10] + b_out ----------------
// 4 lanes per row; LDS w with q-stride 33 to dodge the 4-way bank conflict.

__global__ __launch_bounds__(256) void out_gemm_k(const float* __restrict__ act, const float* __restrict__ w,
                                                  const float* __restrict__ bo, float* __restrict__ out, int N) {
    __shared__ float wT[10 * 132];   // class c at wT[c*132 + q*33 + k], feature = 32q + k
    int t = threadIdx.x;
    for (int i = t; i < 1280; i += 256) {
        int c = i >> 7;
        int j = i & 127;                         // feature index
        wT[c * 132 + j + (j >> 5)] = w[j * 10 + c];
    }
    __syncthreads();

    int r = t >> 2;                               // row within block (0..63)
    int q = t & 3;                                // feature quarter
    int row = blockIdx.x * 64 + r;
    if (row >= N) return;

    const float* ap = act + (size_t)row * F + q * 32;
    float a[32];
#pragma unroll
    for (int i = 0; i < 8; ++i) {
        float4 v4 = *(const float4*)(ap + i * 4);
        a[i * 4 + 0] = v4.x; a[i * 4 + 1] = v4.y;
        a[i * 4 + 2] = v4.z; a[i * 4 + 3] = v4.w;
    }

    float acc[10];
#pragma unroll
    for (int c = 0; c < 10; ++c) {
        const float* wp = &wT[c * 132 + q * 33];
        float s = 0.f;
#pragma unroll
        for (int k = 0; k < 32; ++k) s = fmaf(a[k], wp[k], s);
        acc[c] = s;
    }

#pragma unroll
    for (int c = 0; c < 10; ++c) {
        acc[c] += __shfl_xor(acc[c], 1, 64);
        acc[c] += __shfl_xor(acc[c], 2, 64);
        acc[c] += bo[c];
    }

#pragma unroll
    for (int c = q; c < 10; c += 4) out[(size_t)row * 10 + c] = acc[c];
}

// ---------------- launch ----------------

extern "C" void kernel_launch(void* const* d_in, const int* in_sizes, int n_in,
                              void* d_out, int out_size, void* d_ws, size_t ws_size,
                              hipStream_t stream) {
    const float* x = (const float*)d_in[0];
    const int* ei = (const int*)d_in[1];
    const int* src = ei;
    const int* dst = ei + NE;
    const float *W[4], *B[4], *G[4], *BE[4], *Mn[4], *V[4];
    for (int l = 0; l < 4; ++l) {
        W[l]  = (const float*)d_in[2 + 6 * l];
        B[l]  = (const float*)d_in[3 + 6 * l];
        G[l]  = (const float*)d_in[4 + 6 * l];
        BE[l] = (const float*)d_in[5 + 6 * l];
        Mn[l] = (const float*)d_in[6 + 6 * l];
        V[l]  = (const float*)d_in[7 + 6 * l];
    }
    const float* w_out = (const float*)d_in[26];
    const float* b_out = (const float*)d_in[27];
    float* out = (float*)d_out;

    char* ws = (char*)d_ws;
    size_t off = 0;
    auto alloc = [&](size_t bytes) {
        void* p = ws + off;
        off = (off + bytes + 255) & ~(size_t)255;
        return p;
    };
    int*   deg8 = (int*)alloc((size_t)8 * NN * 4);
    int*   rp   = (int*)alloc((NN + 1) * 4);
    int*   fillc= (int*)alloc((size_t)8 * NN * 4);
    int*   bsum = (int*)alloc(256 * 4);
    int*   bpre = (int*)alloc(256 * 4);
    float* dinv = (float*)alloc(NN * 4);
    int*   col  = (int*)alloc((size_t)NE * 4);
    unsigned short* hb   = (unsigned short*)alloc((size_t)NN * F * 2);
    unsigned short* acth = (unsigned short*)alloc((size_t)NN * F * 2);
    unsigned short* actl = (unsigned short*)alloc((size_t)NN * F * 2);
    float* act  = (float*)alloc((size_t)NN * F * 4);
    unsigned short* whp  = (unsigned short*)alloc(4 * 16384 * 2);
    unsigned short* wlp  = (unsigned short*)alloc(4 * 16384 * 2);

    hipMemsetAsync(deg8, 0, (size_t)8 * NN * 4, stream);
    pack_all_k<<<256, 256, 0, stream>>>(W[0], W[1], W[2], W[3], whp, wlp);
    hist_k<<<(NE / 8 + 255) / 256, 256, 0, stream>>>(dst, deg8, NE);
    block_sums_k<<<(NN + 255) / 256, 256, 0, stream>>>(deg8, bsum, NN);
    scan_partials_k<<<1, 256, 0, stream>>>(bsum, bpre, (NN + 255) / 256);
    scan_final_k<<<(NN + 255) / 256, 256, 0, stream>>>(deg8, bpre, rp, fillc, dinv, NN, NE);

    // fill (CSR scatter) and layer-1 GEMM interleaved 1:2 in one grid
    fused_fill_gemm_k<<<FUSEDB, 256, 0, stream>>>(src, dst, fillc, col, NE,
                                                  x, whp, wlp, dinv, hb, NN);
    agg_split_k<<<(NN + 3) / 4, 256, 0, stream>>>(hb, rp, col, dinv, B[0], G[0], BE[0], Mn[0], V[0], acth, actl, NN);
    // layers 2-3: split path
    for (int l = 1; l < 3; ++l) {
        gemm_split_k<<<(NN + 63) / 64, 256, 0, stream>>>(acth, actl, whp + l * 16384, wlp + l * 16384, dinv, hb, NN);
        agg_split_k<<<(NN + 3) / 4, 256, 0, stream>>>(hb, rp, col, dinv, B[l], G[l], BE[l], Mn[l], V[l], acth, actl, NN);
    }
    // layer 4: split gemm + fp32 agg + small output GEMM
    gemm_split_k<<<(NN + 63) / 64, 256, 0, stream>>>(acth, actl, whp + 3 * 16384, wlp + 3 * 16384, dinv, hb, NN);
    agg_fp32_k<<<(NN + 3) / 4, 256, 0, stream>>>(hb, rp, col, dinv, B[3], G[3], BE[3], Mn[3], V[3], act, NN);
    out_gemm_k<<<(NN + 63) / 64, 256, 0, stream>>>(act, w_out, b_out, out, NN);
}

// Round 11
// 307.779 us; speedup vs baseline: 1.1003x; 1.1003x over previous
//
#include <hip/hip_runtime.h>

#define NN 50000
#define NE 800000
#define F 128
#define EPS 1e-5f
#define PACKB 256    // pack blocks (65536 elems / 256)
#define HISTB 391    // ceil(NE / 2048): hist blocks, 8 edges/thread
#define FILLB 391    // ceil(NE / 2048): fill blocks, 8 edges/thread (matches hist chunking)
#define GEMMB 782    // ceil(NN / 64) gemm blocks
#define FUSEDB (FILLB + GEMMB)

typedef __attribute__((ext_vector_type(8))) short bf16x8;
typedef __attribute__((ext_vector_type(4))) float f32x4;

__device__ inline unsigned short f2bf_rn(float f) {
    unsigned u = __builtin_bit_cast(unsigned, f);
    u += 0x7fffu + ((u >> 16) & 1u);
    return (unsigned short)(u >> 16);
}
__device__ inline float bf2f(unsigned short h) {
    unsigned u = ((unsigned)h) << 16;
    return __builtin_bit_cast(float, u);
}
__device__ inline float bflo(unsigned u) {                 // low bf16 of packed pair -> f32
    return __builtin_bit_cast(float, u << 16);
}
__device__ inline float bfhi(unsigned u) {                 // high bf16 of packed pair -> f32
    return __builtin_bit_cast(float, u & 0xffff0000u);
}

// ---------------- FUSED W-pack + degree histogram ----------------
// pack (256 blocks, VALU-only, 2us) and hist (391 blocks, atomic-bound, 12us)
// are independent -> interleaved in one dispatch (R9-proven trick). hist ordinal
// hb = bid-256 keeps hb&7 == bid&7 (256 = 0 mod 8), so the edge->group map is
// IDENTICAL to the fill pass's fb&7 chunking.

__global__ __launch_bounds__(256) void pack_hist_k(const float* __restrict__ W0, const float* __restrict__ W1,
                                                   const float* __restrict__ W2, const float* __restrict__ W3,
                                                   unsigned short* __restrict__ wh, unsigned short* __restrict__ wl,
                                                   const int* __restrict__ dst, int* __restrict__ deg8, int E) {
    const int bid = blockIdx.x;
    if (bid < PACKB) {
        // ---- pack body: W into MFMA B-fragment order (bf16 hi/lo), all 4 layers ----
        int gidx = bid * 256 + threadIdx.x;            // 0..65535
        int layer = gidx >> 14;
        int idx = gidx & 16383;
        const float* W = (layer == 0) ? W0 : (layer == 1) ? W1 : (layer == 2) ? W2 : W3;
        int i = idx & 7;
        int l = (idx >> 3) & 63;
        int n = (idx >> 9) & 7;
        int s = idx >> 12;
        int h = i >> 2, j = i & 3;
        int k = 32 * s + 4 * (l >> 4) + j + 16 * h;
        int c = 16 * n + (l & 15);
        float f = W[k * F + c];
        unsigned short hb = f2bf_rn(f);
        float rest = f - bf2f(hb);
        unsigned short lb = f2bf_rn(rest);
        wh[gidx] = hb;
        wl[gidx] = lb;
        return;
    }
    // ---- hist body: 8 edges/thread, hist-ordinal hb = bid - PACKB ----
    int hb = bid - PACKB;
    int base = (hb * 256 + threadIdx.x) * 8;
    if (base >= E) return;
    int* dg = deg8 + (hb & 7) * NN;
    int4 d0 = *(const int4*)&dst[base];
    int4 d1 = *(const int4*)&dst[base + 4];
    atomicAdd(&dg[d0.x], 1); atomicAdd(&dg[d0.y], 1);
    atomicAdd(&dg[d0.z], 1); atomicAdd(&dg[d0.w], 1);
    atomicAdd(&dg[d1.x], 1); atomicAdd(&dg[d1.y], 1);
    atomicAdd(&dg[d1.z], 1); atomicAdd(&dg[d1.w], 1);
}

__global__ __launch_bounds__(256) void block_sums_k(const int* __restrict__ deg8, int* __restrict__ bsum, int N) {
    __shared__ int s[256];
    int t = threadIdx.x;
    int i = blockIdx.x * 256 + t;
    int v = 0;
    if (i < N) {
#pragma unroll
        for (int g = 0; g < 8; ++g) v += deg8[g * NN + i];
    }
    s[t] = v;
    __syncthreads();
    for (int off = 128; off > 0; off >>= 1) {
        if (t < off) s[t] += s[t + off];
        __syncthreads();
    }
    if (t == 0) bsum[blockIdx.x] = s[0];
}

__global__ __launch_bounds__(256) void scan_partials_k(const int* __restrict__ bsum, int* __restrict__ bpre, int nb) {
    __shared__ int s[256];
    int t = threadIdx.x;
    int v = (t < nb) ? bsum[t] : 0;
    s[t] = v;
    __syncthreads();
    for (int off = 1; off < 256; off <<= 1) {
        int add = (t >= off) ? s[t - off] : 0;
        __syncthreads();
        s[t] += add;
        __syncthreads();
    }
    if (t < nb) bpre[t] = s[t] - v;   // exclusive
}

__global__ __launch_bounds__(256) void scan_final_k(const int* __restrict__ deg8, const int* __restrict__ bpre,
                                                    int* __restrict__ rp, int* __restrict__ fillcur,
                                                    float* __restrict__ dinv, int N, int E) {
    __shared__ int s[256];
    int t = threadIdx.x;
    int i = blockIdx.x * 256 + t;
    int c[8];
    int v = 0;
#pragma unroll
    for (int g = 0; g < 8; ++g) {
        c[g] = (i < N) ? deg8[g * NN + i] : 0;
        v += c[g];
    }
    s[t] = v;
    __syncthreads();
    for (int off = 1; off < 256; off <<= 1) {
        int add = (t >= off) ? s[t - off] : 0;
        __syncthreads();
        s[t] += add;
        __syncthreads();
    }
    int excl = s[t] - v + bpre[blockIdx.x];
    if (i < N) {
        rp[i] = excl;
        int run = excl;
#pragma unroll
        for (int g = 0; g < 8; ++g) {
            fillcur[g * NN + i] = run;   // per-group cursor start
            run += c[g];
        }
        dinv[i] = rsqrtf((float)v + 1.0f);
    }
    if (i == 0) rp[N] = E;
}

// ---------------- FUSED fill + layer-1 GEMM, INTERLEAVED grid (R9-proven) ----------------
// 1 fill : 2 gemm interleave so both kinds are co-resident from dispatch 0 ->
// atomic-bounce-bound fill overlaps MFMA/HBM-bound gemm (dur ~56us vs ~65 serial).
// Plain col stores: NT stores were tried (R10) and REGRESSED (WRITE 61->67MB) —
// NT forfeits L2 write-combining, costing more than the line bounce it avoids.

__global__ __launch_bounds__(256, 2) void fused_fill_gemm_k(const int* __restrict__ src, const int* __restrict__ dst,
                                                            int* __restrict__ fillcur, int* __restrict__ col, int E,
                                                            const float* __restrict__ A,
                                                            const unsigned short* __restrict__ wh,
                                                            const unsigned short* __restrict__ wl,
                                                            const float* __restrict__ dinv,
                                                            unsigned short* __restrict__ Hb, int M) {
    const int bid = blockIdx.x;
    if (bid % 3 == 0) {
        // ---- fill body (8 edges/thread), fill-ordinal fb = bid/3 ----
        int fb = bid / 3;                       // 0..FILLB-1, chunk of 2048 edges
        int base = (fb * 256 + threadIdx.x) * 8;
        if (base >= E) return;
        int* fc = fillcur + (fb & 7) * NN;      // same edge->group map as hist
        int4 d0 = *(const int4*)&dst[base];
        int4 d1 = *(const int4*)&dst[base + 4];
        int4 s0 = *(const int4*)&src[base];
        int4 s1 = *(const int4*)&src[base + 4];
        int p0 = atomicAdd(&fc[d0.x], 1);
        int p1 = atomicAdd(&fc[d0.y], 1);
        int p2 = atomicAdd(&fc[d0.z], 1);
        int p3 = atomicAdd(&fc[d0.w], 1);
        int p4 = atomicAdd(&fc[d1.x], 1);
        int p5 = atomicAdd(&fc[d1.y], 1);
        int p6 = atomicAdd(&fc[d1.z], 1);
        int p7 = atomicAdd(&fc[d1.w], 1);
        col[p0] = s0.x; col[p1] = s0.y; col[p2] = s0.z; col[p3] = s0.w;
        col[p4] = s1.x; col[p5] = s1.y; col[p6] = s1.z; col[p7] = s1.w;
        return;
    }

    // ---- gemm_conv body, gemm-ordinal gb = bid - bid/3 - 1 ----
    const int gb = bid - bid / 3 - 1;           // 0..GEMMB-1
    const int tid = threadIdx.x;
    const int w = tid >> 6;
    const int l = tid & 63;
    const int lr = l & 15;
    const int g = l >> 4;
    const int row0 = gb * 64;
    const int arow = min(row0 + w * 16 + lr, M - 1);
    const float* ap = A + (size_t)arow * F + g * 4;

    float4 af[4][2];
#pragma unroll
    for (int s = 0; s < 4; ++s) {
        af[s][0] = *(const float4*)(ap + s * 32);
        af[s][1] = *(const float4*)(ap + s * 32 + 16);
    }

    const unsigned short* bh = wh + (size_t)l * 8;
    const unsigned short* bl = wl + (size_t)l * 8;
    bf16x8 Bh[2][8], Bl[2][8];
#pragma unroll
    for (int n = 0; n < 8; ++n) {
        Bh[0][n] = *(const bf16x8*)(bh + (size_t)n * 512);
        Bl[0][n] = *(const bf16x8*)(bl + (size_t)n * 512);
    }

    bf16x8 ah[4], al[4];
#pragma unroll
    for (int s = 0; s < 4; ++s) {
#pragma unroll
        for (int i = 0; i < 8; ++i) {
            float f = (i < 4) ? (&af[s][0].x)[i] : (&af[s][1].x)[i - 4];
            unsigned short hb = f2bf_rn(f);
            ah[s][i] = (short)hb;
            al[s][i] = (short)f2bf_rn(f - bf2f(hb));
        }
    }

    f32x4 acc[8] = {};
#pragma unroll
    for (int s = 0; s < 4; ++s) {
        const int cur = s & 1, nxt = cur ^ 1;
        if (s < 3) {
#pragma unroll
            for (int n = 0; n < 8; ++n) {
                Bh[nxt][n] = *(const bf16x8*)(bh + (size_t)((s + 1) * 8 + n) * 512);
                Bl[nxt][n] = *(const bf16x8*)(bl + (size_t)((s + 1) * 8 + n) * 512);
            }
        }
#pragma unroll
        for (int n = 0; n < 8; ++n) {
            acc[n] = __builtin_amdgcn_mfma_f32_16x16x32_bf16(ah[s], Bh[cur][n], acc[n], 0, 0, 0);
            acc[n] = __builtin_amdgcn_mfma_f32_16x16x32_bf16(al[s], Bh[cur][n], acc[n], 0, 0, 0);
            acc[n] = __builtin_amdgcn_mfma_f32_16x16x32_bf16(ah[s], Bl[cur][n], acc[n], 0, 0, 0);
        }
    }

    float di[4];
#pragma unroll
    for (int r = 0; r < 4; ++r) {
        int row = row0 + w * 16 + g * 4 + r;
        di[r] = (row < M) ? dinv[row] : 0.f;
    }
#pragma unroll
    for (int n = 0; n < 8; ++n) {
#pragma unroll
        for (int r = 0; r < 4; ++r) {
            int row = row0 + w * 16 + g * 4 + r;
            if (row < M) Hb[(size_t)row * F + n * 16 + lr] = f2bf_rn(acc[n][r] * di[r]);
        }
    }
}

// ---------------- MFMA GEMM, layers 2-4: A pre-split hi/lo bf16 in FRAGMENT order ----------------
// acth/actl row layout: element f = 32s+16h+4g+j stored at pos = (g*4+s)*8 + 4h+j.

__global__ __launch_bounds__(256, 2) void gemm_split_k(const unsigned short* __restrict__ Ah,
                                                       const unsigned short* __restrict__ Al,
                                                       const unsigned short* __restrict__ wh,
                                                       const unsigned short* __restrict__ wl,
                                                       const float* __restrict__ dinv,
                                                       unsigned short* __restrict__ Hb, int M) {
    const int tid = threadIdx.x;
    const int w = tid >> 6;
    const int l = tid & 63;
    const int lr = l & 15;
    const int g = l >> 4;
    const int row0 = blockIdx.x * 64;
    const int arow = min(row0 + w * 16 + lr, M - 1);
    const unsigned short* ahp = Ah + (size_t)arow * F;
    const unsigned short* alp = Al + (size_t)arow * F;

    bf16x8 ah[4], al[4];
#pragma unroll
    for (int s = 0; s < 4; ++s) {
        ah[s] = *(const bf16x8*)(ahp + (g * 4 + s) * 8);
        al[s] = *(const bf16x8*)(alp + (g * 4 + s) * 8);
    }

    const unsigned short* bh = wh + (size_t)l * 8;
    const unsigned short* bl = wl + (size_t)l * 8;
    bf16x8 Bh[2][8], Bl[2][8];
#pragma unroll
    for (int n = 0; n < 8; ++n) {
        Bh[0][n] = *(const bf16x8*)(bh + (size_t)n * 512);
        Bl[0][n] = *(const bf16x8*)(bl + (size_t)n * 512);
    }

    f32x4 acc[8] = {};
#pragma unroll
    for (int s = 0; s < 4; ++s) {
        const int cur = s & 1, nxt = cur ^ 1;
        if (s < 3) {
#pragma unroll
            for (int n = 0; n < 8; ++n) {
                Bh[nxt][n] = *(const bf16x8*)(bh + (size_t)((s + 1) * 8 + n) * 512);
                Bl[nxt][n] = *(const bf16x8*)(bl + (size_t)((s + 1) * 8 + n) * 512);
            }
        }
#pragma unroll
        for (int n = 0; n < 8; ++n) {
            acc[n] = __builtin_amdgcn_mfma_f32_16x16x32_bf16(ah[s], Bh[cur][n], acc[n], 0, 0, 0);
            acc[n] = __builtin_amdgcn_mfma_f32_16x16x32_bf16(al[s], Bh[cur][n], acc[n], 0, 0, 0);
            acc[n] = __builtin_amdgcn_mfma_f32_16x16x32_bf16(ah[s], Bl[cur][n], acc[n], 0, 0, 0);
        }
    }

    float di[4];
#pragma unroll
    for (int r = 0; r < 4; ++r) {
        int row = row0 + w * 16 + g * 4 + r;
        di[r] = (row < M) ? dinv[row] : 0.f;
    }
#pragma unroll
    for (int n = 0; n < 8; ++n) {
#pragma unroll
        for (int r = 0; r < 4; ++r) {
            int row = row0 + w * 16 + g * 4 + r;
            if (row < M) Hb[(size_t)row * F + n * 16 + lr] = f2bf_rn(acc[n][r] * di[r]);
        }
    }
}

// ---------------- aggregation core (R6-proven) ----------------
// Full 16-batches: no clamp/mask, 32-bit saddr addressing; ONE masked tail batch.
// Plain col loads (NT loads regressed in R10 — col L2-caching is worth more
// than the Hb lines it evicts).

__device__ inline void gather_row16(const unsigned short* __restrict__ Hb, const int* __restrict__ col,
                                    int e0, int e1, int lane, float& sxo, float& syo) {
    const unsigned char* hbb = (const unsigned char*)Hb;
    const unsigned loff = (unsigned)lane << 2;
    float sx = 0.f, sy = 0.f;
    int e = e0;
    int nfull = (e1 - e0) >> 4;
    for (int bt = 0; bt < nfull; ++bt, e += 16) {
        int c[16];
#pragma unroll
        for (int j = 0; j < 16; ++j) c[j] = col[e + j];
        unsigned hv[16];
#pragma unroll
        for (int j = 0; j < 16; ++j) hv[j] = *(const unsigned*)(hbb + (((unsigned)c[j] << 8) + loff));
#pragma unroll
        for (int j = 0; j < 16; ++j) { sx += bflo(hv[j]); sy += bfhi(hv[j]); }
    }
    if (e < e1) {
        int c[16];
#pragma unroll
        for (int j = 0; j < 16; ++j) c[j] = col[min(e + j, e1 - 1)];
        unsigned hv[16];
#pragma unroll
        for (int j = 0; j < 16; ++j) hv[j] = *(const unsigned*)(hbb + (((unsigned)c[j] << 8) + loff));
#pragma unroll
        for (int j = 0; j < 16; ++j) hv[j] = (e + j < e1) ? hv[j] : 0u;
#pragma unroll
        for (int j = 0; j < 16; ++j) { sx += bflo(hv[j]); sy += bfhi(hv[j]); }
    }
    sxo = sx; syo = sy;
}

// ---------------- agg + BN + ReLU, layers 1-3: write hi/lo bf16 act in fragment order ----------------

__global__ __launch_bounds__(256) void agg_split_k(const unsigned short* __restrict__ Hb, const int* __restrict__ rp,
                                                   const int* __restrict__ col, const float* __restrict__ dinv,
                                                   const float* __restrict__ b, const float* __restrict__ g,
                                                   const float* __restrict__ be, const float* __restrict__ m,
                                                   const float* __restrict__ v,
                                                   unsigned short* __restrict__ acth, unsigned short* __restrict__ actl,
                                                   int N) {
    int wid = threadIdx.x >> 6;
    int lane = threadIdx.x & 63;
    int row = blockIdx.x * 4 + wid;
    if (row >= N) return;

    int e0 = rp[row], e1 = rp[row + 1];
    float sx, sy;
    gather_row16(Hb, col, e0, e1, lane, sx, sy);

    float di = dinv[row];
    unsigned hs = *(const unsigned*)((const unsigned char*)Hb + (((unsigned)row << 8) + ((unsigned)lane << 2)));
    float hsx = bflo(hs);
    float hsy = bfhi(hs);
    int f0 = 2 * lane, f1 = f0 + 1;
    float rx = (sx + hsx) * di + b[f0];
    float ry = (sy + hsy) * di + b[f1];
    float ax = rsqrtf(v[f0] + EPS) * g[f0];
    float ay = rsqrtf(v[f1] + EPS) * g[f1];
    rx = fmaf(rx - m[f0], ax, be[f0]);
    ry = fmaf(ry - m[f1], ay, be[f1]);
    rx = fmaxf(rx, 0.f);
    ry = fmaxf(ry, 0.f);

    // hi/lo split, stored at fragment-order position of f0 (f1 = f0+1 is adjacent)
    unsigned short hx = f2bf_rn(rx);
    unsigned short lx = f2bf_rn(rx - bf2f(hx));
    unsigned short hy = f2bf_rn(ry);
    unsigned short ly = f2bf_rn(ry - bf2f(hy));
    int j = f0 & 3, gq = (f0 >> 2) & 3, h = (f0 >> 4) & 1, s = f0 >> 5;
    int pos = (gq * 4 + s) * 8 + h * 4 + j;
    *(unsigned*)&acth[(size_t)row * F + pos] = (unsigned)hx | ((unsigned)hy << 16);
    *(unsigned*)&actl[(size_t)row * F + pos] = (unsigned)lx | ((unsigned)ly << 16);
}

// ---------------- agg + BN + ReLU, layer 4: write fp32 act ----------------

__global__ __launch_bounds__(256) void agg_fp32_k(const unsigned short* __restrict__ Hb, const int* __restrict__ rp,
                                                  const int* __restrict__ col, const float* __restrict__ dinv,
                                                  const float* __restrict__ b, const float* __restrict__ g,
                                                  const float* __restrict__ be, const float* __restrict__ m,
                                                  const float* __restrict__ v,
                                                  float* __restrict__ out, int N) {
    int wid = threadIdx.x >> 6;
    int lane = threadIdx.x & 63;
    int row = blockIdx.x * 4 + wid;
    if (row >= N) return;

    int e0 = rp[row], e1 = rp[row + 1];
    float sx, sy;
    gather_row16(Hb, col, e0, e1, lane, sx, sy);

    float di = dinv[row];
    unsigned hs = *(const unsigned*)((const unsigned char*)Hb + (((unsigned)row << 8) + ((unsigned)lane << 2)));
    float hsx = bflo(hs);
    float hsy = bfhi(hs);
    int f0 = 2 * lane, f1 = f0 + 1;
    float rx = (sx + hsx) * di + b[f0];
    float ry = (sy + hsy) * di + b[f1];
    float ax = rsqrtf(v[f0] + EPS) * g[f0];
    float ay = rsqrtf(v[f1] + EPS) * g[f1];
    rx = fmaf(rx - m[f0], ax, be[f0]);
    ry = fmaf(ry - m[f1], ay, be[f1]);
    rx = fmaxf(rx, 0.f);
    ry = fmaxf(ry, 0.f);
    float2 o = {rx, ry};
    *(float2*)&out[(size_t)row * F + 2 * lane] = o;
}

// ---------------- final: out[N,10] = act @ w_out[128,10] + b_out ----------------
// 4 lanes per row; LDS w with q-stride 33 to dodge the 4-way bank conflict.

__global__ __launch_bounds__(256) void out_gemm_k(const float* __restrict__ act, const float* __restrict__ w,
                                                  const float* __restrict__ bo, float* __restrict__ out, int N) {
    __shared__ float wT[10 * 132];   // class c at wT[c*132 + q*33 + k], feature = 32q + k
    int t = threadIdx.x;
    for (int i = t; i < 1280; i += 256) {
        int c = i >> 7;
        int j = i & 127;                         // feature index
        wT[c * 132 + j + (j >> 5)] = w[j * 10 + c];
    }
    __syncthreads();

    int r = t >> 2;                               // row within block (0..63)
    int q = t & 3;                                // feature quarter
    int row = blockIdx.x * 64 + r;
    if (row >= N) return;

    const float* ap = act + (size_t)row * F + q * 32;
    float a[32];
#pragma unroll
    for (int i = 0; i < 8; ++i) {
        float4 v4 = *(const float4*)(ap + i * 4);
        a[i * 4 + 0] = v4.x; a[i * 4 + 1] = v4.y;
        a[i * 4 + 2] = v4.z; a[i * 4 + 3] = v4.w;
    }

    float acc[10];
#pragma unroll
    for (int c = 0; c < 10; ++c) {
        const float* wp = &wT[c * 132 + q * 33];
        float s = 0.f;
#pragma unroll
        for (int k = 0; k < 32; ++k) s = fmaf(a[k], wp[k], s);
        acc[c] = s;
    }

#pragma unroll
    for (int c = 0; c < 10; ++c) {
        acc[c] += __shfl_xor(acc[c], 1, 64);
        acc[c] += __shfl_xor(acc[c], 2, 64);
        acc[c] += bo[c];
    }

#pragma unroll
    for (int c = q; c < 10; c += 4) out[(size_t)row * 10 + c] = acc[c];
}

// ---------------- launch ----------------

extern "C" void kernel_launch(void* const* d_in, const int* in_sizes, int n_in,
                              void* d_out, int out_size, void* d_ws, size_t ws_size,
                              hipStream_t stream) {
    const float* x = (const float*)d_in[0];
    const int* ei = (const int*)d_in[1];
    const int* src = ei;
    const int* dst = ei + NE;
    const float *W[4], *B[4], *G[4], *BE[4], *Mn[4], *V[4];
    for (int l = 0; l < 4; ++l) {
        W[l]  = (const float*)d_in[2 + 6 * l];
        B[l]  = (const float*)d_in[3 + 6 * l];
        G[l]  = (const float*)d_in[4 + 6 * l];
        BE[l] = (const float*)d_in[5 + 6 * l];
        Mn[l] = (const float*)d_in[6 + 6 * l];
        V[l]  = (const float*)d_in[7 + 6 * l];
    }
    const float* w_out = (const float*)d_in[26];
    const float* b_out = (const float*)d_in[27];
    float* out = (float*)d_out;

    char* ws = (char*)d_ws;
    size_t off = 0;
    auto alloc = [&](size_t bytes) {
        void* p = ws + off;
        off = (off + bytes + 255) & ~(size_t)255;
        return p;
    };
    int*   deg8 = (int*)alloc((size_t)8 * NN * 4);
    int*   rp   = (int*)alloc((NN + 1) * 4);
    int*   fillc= (int*)alloc((size_t)8 * NN * 4);
    int*   bsum = (int*)alloc(256 * 4);
    int*   bpre = (int*)alloc(256 * 4);
    float* dinv = (float*)alloc(NN * 4);
    int*   col  = (int*)alloc((size_t)NE * 4);
    unsigned short* hb   = (unsigned short*)alloc((size_t)NN * F * 2);
    unsigned short* acth = (unsigned short*)alloc((size_t)NN * F * 2);
    unsigned short* actl = (unsigned short*)alloc((size_t)NN * F * 2);
    float* act  = (float*)alloc((size_t)NN * F * 4);
    unsigned short* whp  = (unsigned short*)alloc(4 * 16384 * 2);
    unsigned short* wlp  = (unsigned short*)alloc(4 * 16384 * 2);

    hipMemsetAsync(deg8, 0, (size_t)8 * NN * 4, stream);
    // W-pack (256 blocks) + degree hist (391 blocks) in one interleaved dispatch
    pack_hist_k<<<PACKB + HISTB, 256, 0, stream>>>(W[0], W[1], W[2], W[3], whp, wlp, dst, deg8, NE);
    block_sums_k<<<(NN + 255) / 256, 256, 0, stream>>>(deg8, bsum, NN);
    scan_partials_k<<<1, 256, 0, stream>>>(bsum, bpre, (NN + 255) / 256);
    scan_final_k<<<(NN + 255) / 256, 256, 0, stream>>>(deg8, bpre, rp, fillc, dinv, NN, NE);

    // fill (CSR scatter) and layer-1 GEMM interleaved 1:2 in one grid
    fused_fill_gemm_k<<<FUSEDB, 256, 0, stream>>>(src, dst, fillc, col, NE,
                                                  x, whp, wlp, dinv, hb, NN);
    agg_split_k<<<(NN + 3) / 4, 256, 0, stream>>>(hb, rp, col, dinv, B[0], G[0], BE[0], Mn[0], V[0], acth, actl, NN);
    // layers 2-3: split path
    for (int l = 1; l < 3; ++l) {
        gemm_split_k<<<(NN + 63) / 64, 256, 0, stream>>>(acth, actl, whp + l * 16384, wlp + l * 16384, dinv, hb, NN);
        agg_split_k<<<(NN + 3) / 4, 256, 0, stream>>>(hb, rp, col, dinv, B[l], G[l], BE[l], Mn[l], V[l], acth, actl, NN);
    }
    // layer 4: split gemm + fp32 agg + small output GEMM
    gemm_split_k<<<(NN + 63) / 64, 256, 0, stream>>>(acth, actl, whp + 3 * 16384, wlp + 3 * 16384, dinv, hb, NN);
    agg_fp32_k<<<(NN + 3) / 4, 256, 0, stream>>>(hb, rp, col, dinv, B[3], G[3], BE[3], Mn[3], V[3], act, NN);
    out_gemm_k<<<(NN + 63) / 64, 256, 0, stream>>>(act, w_out, b_out, out, NN);
}